// Round 1
// baseline (10151.334 us; speedup 1.0000x reference)
//
#include <hip/hip_runtime.h>
#include <cstdint>
#include <cstddef>

#define T_SEQ 4096
#define HSZ   512
#define NGATE 2048   // 4*HSZ
#define DIN   1024
#define NB0   32     // layer-0 blocks per direction
#define HB0   16     // h-elements per layer-0 block
#define NB1   64     // layer-1 blocks per direction
#define HB1   8      // h-elements per layer-1 block
#define CH    132    // skewed LDS chunk stride (128 + 4)

typedef unsigned long long u64;
typedef unsigned int u32;

__device__ __forceinline__ u64 exld(const u64* p) {
  return __hip_atomic_load(p, __ATOMIC_RELAXED, __HIP_MEMORY_SCOPE_AGENT);
}
__device__ __forceinline__ void exst(u64* p, u64 v) {
  __hip_atomic_store(p, v, __ATOMIC_RELAXED, __HIP_MEMORY_SCOPE_AGENT);
}
__device__ __forceinline__ int pgld(const u32* p) {
  return (int)__hip_atomic_load(p, __ATOMIC_RELAXED, __HIP_MEMORY_SCOPE_AGENT);
}
__device__ __forceinline__ void pgst(u32* p, u32 v) {
  __hip_atomic_store(p, v, __ATOMIC_RELAXED, __HIP_MEMORY_SCOPE_AGENT);
}

// fast activations: v_rcp + v_exp, no div sequences, no libm tanh
__device__ __forceinline__ float frcp(float x) { return __builtin_amdgcn_rcpf(x); }
__device__ __forceinline__ float fsig(float x) { return frcp(1.f + __expf(-x)); }
__device__ __forceinline__ float ftnh(float x) { return 1.f - 2.f * frcp(1.f + __expf(2.f * x)); }

// ---------------- init: zero exchange slots (epoch0 == h_0 == 0) + progress flags ----------------
__global__ void init_sync_kernel(u64* ex, u32* prog) {
  const int tid = blockIdx.x * blockDim.x + threadIdx.x;
  if (tid < 2 * 2 * 4 * HSZ) exst(&ex[tid], 0ull);
  if (tid < 2 * (NB0 + NB1)) pgst(&prog[tid], 0u);
}

// ---------------- fp32 GEMM with bias: P[t,r] = sum_k X[t,k]*W[r,k] + bi[r] + bh[r] ----------------
__global__ __launch_bounds__(256, 2)
void gemm_bias_kernel(const float* __restrict__ Xf, const float* __restrict__ Xb,
                      const float* __restrict__ Wf, const float* __restrict__ Wb,
                      const float* __restrict__ bif, const float* __restrict__ bhf,
                      const float* __restrict__ bib, const float* __restrict__ bhb,
                      float* __restrict__ Pf, float* __restrict__ Pb, int K)
{
  const int dir = blockIdx.z;
  const float* X  = dir ? Xb  : Xf;
  const float* W  = dir ? Wb  : Wf;
  const float* bi = dir ? bib : bif;
  const float* bh = dir ? bhb : bhf;
  float* P        = dir ? Pb  : Pf;

  const int m0 = blockIdx.x * 128;
  const int n0 = blockIdx.y * 128;
  const int tid = threadIdx.x;
  const int lr = tid >> 1;
  const int lk = (tid & 1) * 8;

  __shared__ float As[16*128];
  __shared__ float Bs[16*128];

  float acc[8][8];
  #pragma unroll
  for (int i = 0; i < 8; ++i)
    #pragma unroll
    for (int j = 0; j < 8; ++j) acc[i][j] = 0.f;

  for (int k0 = 0; k0 < K; k0 += 16) {
    const float4 a0 = *(const float4*)(X + (size_t)(m0+lr)*K + k0 + lk);
    const float4 a1 = *(const float4*)(X + (size_t)(m0+lr)*K + k0 + lk + 4);
    const float4 b0 = *(const float4*)(W + (size_t)(n0+lr)*K + k0 + lk);
    const float4 b1 = *(const float4*)(W + (size_t)(n0+lr)*K + k0 + lk + 4);
    __syncthreads();
    As[(lk+0)*128+lr]=a0.x; As[(lk+1)*128+lr]=a0.y; As[(lk+2)*128+lr]=a0.z; As[(lk+3)*128+lr]=a0.w;
    As[(lk+4)*128+lr]=a1.x; As[(lk+5)*128+lr]=a1.y; As[(lk+6)*128+lr]=a1.z; As[(lk+7)*128+lr]=a1.w;
    Bs[(lk+0)*128+lr]=b0.x; Bs[(lk+1)*128+lr]=b0.y; Bs[(lk+2)*128+lr]=b0.z; Bs[(lk+3)*128+lr]=b0.w;
    Bs[(lk+4)*128+lr]=b1.x; Bs[(lk+5)*128+lr]=b1.y; Bs[(lk+6)*128+lr]=b1.z; Bs[(lk+7)*128+lr]=b1.w;
    __syncthreads();
    #pragma unroll
    for (int kk = 0; kk < 16; ++kk) {
      const float4 A0 = *(const float4*)(As + kk*128 + (tid&15)*8);
      const float4 A1 = *(const float4*)(As + kk*128 + (tid&15)*8 + 4);
      const float4 B0 = *(const float4*)(Bs + kk*128 + (tid>>4)*8);
      const float4 B1 = *(const float4*)(Bs + kk*128 + (tid>>4)*8 + 4);
      const float av[8] = {A0.x,A0.y,A0.z,A0.w,A1.x,A1.y,A1.z,A1.w};
      const float bv[8] = {B0.x,B0.y,B0.z,B0.w,B1.x,B1.y,B1.z,B1.w};
      #pragma unroll
      for (int i = 0; i < 8; ++i)
        #pragma unroll
        for (int j = 0; j < 8; ++j) acc[i][j] += av[i]*bv[j];
    }
  }
  const int tm = m0 + (tid&15)*8;
  const int tn = n0 + (tid>>4)*8;
  #pragma unroll
  for (int i = 0; i < 8; ++i) {
    #pragma unroll
    for (int j = 0; j < 8; ++j) {
      const int n = tn + j;
      P[(size_t)(tm+i)*NGATE + n] = acc[i][j] + bi[n] + bh[n];
    }
  }
}

// ---------------- fused persistent recurrence: both layers, both directions, pipelined ----------------
// blocks [0,64): L0 (fwd 0..31, bwd 32..63)   [64,192): L1 (fwd 64..127, bwd 128..191)
// 256 threads/block (4 waves, 1 wave/SIMD at 1 block/CU).
// Lane remap puts all 4 gates of an h-element in one wave -> gate exchange via 3 shfl_xor,
// single barrier per step, xh double-buffered by t&1 (no WAR barrier needed).
// Exchange protocol unchanged: u64 = (epoch<<32)|float_bits in slot epoch&3; lazy progress
// guards give 2-step slack against slot overwrite.
__global__ __launch_bounds__(256, 2)
void fused_recur_kernel(const float* __restrict__ Whh0_f, const float* __restrict__ Whh0_b,
                        const float* __restrict__ Wih1_f, const float* __restrict__ Whh1_f,
                        const float* __restrict__ bih1_f, const float* __restrict__ bhh1_f,
                        const float* __restrict__ Wih1_b, const float* __restrict__ Whh1_b,
                        const float* __restrict__ bih1_b, const float* __restrict__ bhh1_b,
                        const float* __restrict__ P_f, const float* __restrict__ P_b,
                        u64* ex0, u64* ex1, u32* prog0, u32* prog1,
                        float* __restrict__ out)
{
  const int bx  = blockIdx.x;
  const int tid = threadIdx.x;
  const int lane = tid & 63;
  const int wv   = tid >> 6;

  __shared__ float xh[2][8*CH];   // double-buffered skewed chunks

  if (bx < 2*NB0) {
    // ---------------- layer 0 ----------------
    const int dir = (bx >= NB0) ? 1 : 0;
    const int b   = bx - dir*NB0;
    const float* Whh = dir ? Whh0_b : Whh0_f;
    const float* P   = dir ? P_b    : P_f;
    u64* exS   = ex0 + (size_t)dir*4*HSZ;
    u32* prS   = prog0 + dir*NB0;
    u32* prL1  = prog1 + dir*NB1;

    // lane -> (gate g, element e, col-chunk cc); 4 gates of element e are lanes {base,base+1,base+2,base+3}
    const int g  = lane & 3;
    const int e2 = (lane >> 2) & 3;
    const int cc = lane >> 4;            // 0..3, 128 cols each
    const int e  = wv*4 + e2;            // 0..15 per block
    const int grow = g*HSZ + b*HB0 + e;  // global gate-row
    const bool red0 = (cc == 0);
    const bool act  = red0 && (g == 0);

    float4 w[32];
    {
      const float4* wp = (const float4*)(Whh + (size_t)grow*HSZ + cc*128);
      #pragma unroll
      for (int j = 0; j < 32; ++j) w[j] = wp[j];
    }

    float creg = 0.f;
    for (int t = 0; t < T_SEQ; ++t) {
      // P prefetch (issued early; completes under the poll)
      float pv = 0.f;
      if (red0) {
        const int te = dir ? (T_SEQ-1-t) : t;
        pv = P[(size_t)te*NGATE + grow];
      }
      // slot-overwrite guard (lazy; consumers: L0 peers + L1 blocks of this dir)
      if (tid >= 64 && tid < 64+NB0)  { while (pgld(&prS[tid-64])  < t-2) {} }
      if (tid >= 96 && tid < 96+NB1)  { while (pgld(&prL1[tid-96]) < t-2) {} }
      // poll h_t (2 slots/thread), stage into skewed double-buffered LDS
      {
        const u64* sp = exS + (size_t)(t & 3)*HSZ;
        u64 v0 = 0, v1 = 0; bool o0 = false, o1 = false;
        do {
          if (!o0) { u64 v = exld(sp + tid);       if ((u32)(v >> 32) == (u32)t) { v0 = v; o0 = true; } }
          if (!o1) { u64 v = exld(sp + tid + 256); if ((u32)(v >> 32) == (u32)t) { v1 = v; o1 = true; } }
        } while (!(o0 && o1));
        float* xb = xh[t & 1];
        xb[(tid>>7)*CH + (tid & 127)]         = __uint_as_float((u32)v0);
        xb[((tid>>7)+2)*CH + (tid & 127)]     = __uint_as_float((u32)v1);
      }
      __syncthreads();
      if (tid == 0) pgst(&prS[b], (u32)(t+1));   // reads for step t complete -> unblock writers early
      // matvec: lane covers 128 cols (chunk cc) of its row; 4 independent accumulators
      const float4* h4 = (const float4*)(xh[t & 1] + cc*CH);
      float a0=0.f, a1=0.f, a2=0.f, a3=0.f;
      #pragma unroll
      for (int j = 0; j < 32; j += 4) {
        const float4 h0 = h4[j], h1 = h4[j+1], h2 = h4[j+2], h3 = h4[j+3];
        a0 += w[j].x*h0.x   + w[j].y*h0.y   + w[j].z*h0.z   + w[j].w*h0.w;
        a1 += w[j+1].x*h1.x + w[j+1].y*h1.y + w[j+1].z*h1.z + w[j+1].w*h1.w;
        a2 += w[j+2].x*h2.x + w[j+2].y*h2.y + w[j+2].z*h2.z + w[j+2].w*h2.w;
        a3 += w[j+3].x*h3.x + w[j+3].y*h3.y + w[j+3].z*h3.z + w[j+3].w*h3.w;
      }
      float acc = (a0+a1)+(a2+a3);
      acc += __shfl_xor(acc, 16);   // reduce over cc (lane bits 4,5)
      acc += __shfl_xor(acc, 32);
      const float val = acc + pv;   // full row value on cc==0 lanes
      const float fv1 = __shfl_xor(val, 1);
      const float fv2 = __shfl_xor(val, 2);
      const float fv3 = __shfl_xor(val, 3);
      if (act) {
        // lane g=0 holds i; +1 f; +2 g; +3 o
        const float i_s = fsig(val);
        const float f_s = fsig(fv1);
        const float gt  = ftnh(fv2);
        const float o_s = fsig(fv3);
        creg = f_s*creg + i_s*gt;
        const float hnew = o_s*ftnh(creg);
        const int hidx = b*HB0 + e;
        const u64 pkt = ((u64)(u32)(t+1) << 32) | (u64)__float_as_uint(hnew);
        exst(exS + (size_t)((t+1) & 3)*HSZ + hidx, pkt);
        if (t == T_SEQ-1) {
          out[dir*HSZ + hidx]        = creg;   // cell_memories layer 0
          out[2048 + dir*HSZ + hidx] = hnew;   // hidden_states layer 0
        }
      }
    }
  } else {
    // ---------------- layer 1 ----------------
    const int r   = bx - 2*NB0;
    const int dir = (r >= NB1) ? 1 : 0;
    const int b   = r - dir*NB1;
    const float* Wih = dir ? Wih1_b : Wih1_f;
    const float* Whh = dir ? Whh1_b : Whh1_f;
    const float* bi  = dir ? bih1_b : bih1_f;
    const float* bh  = dir ? bhh1_b : bhh1_f;
    u64* exX = ex0 + (size_t)dir*4*HSZ;          // x source = layer-0 outputs
    u64* exS = ex1 + (size_t)dir*4*HSZ;          // self h exchange
    u32* prS = prog1 + dir*NB1;

    const int g  = lane & 3;
    const int eh = (lane >> 2) & 1;
    const int cc = lane >> 3;            // 0..7 (0-3: Wih/x, 4-7: Whh/h)
    const int e  = wv*2 + eh;            // 0..7 per block
    const int grow = g*HSZ + b*HB1 + e;
    const bool red0 = (cc == 0);
    const bool act  = red0 && (g == 0);

    float4 w[32];
    {
      const float* wsrc = (cc < 4) ? (Wih + (size_t)grow*HSZ + cc*128)
                                   : (Whh + (size_t)grow*HSZ + (cc-4)*128);
      const float4* wp = (const float4*)wsrc;
      #pragma unroll
      for (int j = 0; j < 32; ++j) w[j] = wp[j];
    }
    float brow = 0.f;
    if (red0) brow = bi[grow] + bh[grow];

    float creg = 0.f;
    for (int t = 0; t < T_SEQ; ++t) {
      // slot-overwrite guard (consumers of ex1: L1 peers of this dir)
      if (tid >= 64 && tid < 64+NB1) { while (pgld(&prS[tid-64]) < t-2) {} }
      // poll x_t (layer-0 publish, epoch t+1) and own h_t (epoch t): 4 slots/thread
      {
        const u64* px = exX + (size_t)((t+1) & 3)*HSZ;
        const u64* ph = exS + (size_t)(t & 3)*HSZ;
        u64 x0=0, x1=0, h0=0, h1=0;
        bool ox0=false, ox1=false, oh0=false, oh1=false;
        do {
          if (!ox0) { u64 v = exld(px + tid);       if ((u32)(v>>32) == (u32)(t+1)) { x0 = v; ox0 = true; } }
          if (!ox1) { u64 v = exld(px + tid + 256); if ((u32)(v>>32) == (u32)(t+1)) { x1 = v; ox1 = true; } }
          if (!oh0) { u64 v = exld(ph + tid);       if ((u32)(v>>32) == (u32)t)     { h0 = v; oh0 = true; } }
          if (!oh1) { u64 v = exld(ph + tid + 256); if ((u32)(v>>32) == (u32)t)     { h1 = v; oh1 = true; } }
        } while (!(ox0 && ox1 && oh0 && oh1));
        float* xb = xh[t & 1];
        xb[(tid>>7)*CH + (tid & 127)]       = __uint_as_float((u32)x0);   // chunks 0..1
        xb[((tid>>7)+2)*CH + (tid & 127)]   = __uint_as_float((u32)x1);   // chunks 2..3
        xb[(4+(tid>>7))*CH + (tid & 127)]   = __uint_as_float((u32)h0);   // chunks 4..5
        xb[(6+(tid>>7))*CH + (tid & 127)]   = __uint_as_float((u32)h1);   // chunks 6..7
      }
      __syncthreads();
      if (tid == 0) pgst(&prS[b], (u32)(t+1));
      const float4* h4 = (const float4*)(xh[t & 1] + cc*CH);
      float a0=0.f, a1=0.f, a2=0.f, a3=0.f;
      #pragma unroll
      for (int j = 0; j < 32; j += 4) {
        const float4 h0v = h4[j], h1v = h4[j+1], h2v = h4[j+2], h3v = h4[j+3];
        a0 += w[j].x*h0v.x   + w[j].y*h0v.y   + w[j].z*h0v.z   + w[j].w*h0v.w;
        a1 += w[j+1].x*h1v.x + w[j+1].y*h1v.y + w[j+1].z*h1v.z + w[j+1].w*h1v.w;
        a2 += w[j+2].x*h2v.x + w[j+2].y*h2v.y + w[j+2].z*h2v.z + w[j+2].w*h2v.w;
        a3 += w[j+3].x*h3v.x + w[j+3].y*h3v.y + w[j+3].z*h3v.z + w[j+3].w*h3v.w;
      }
      float acc = (a0+a1)+(a2+a3);
      acc += __shfl_xor(acc, 8);    // reduce over cc (lane bits 3,4,5)
      acc += __shfl_xor(acc, 16);
      acc += __shfl_xor(acc, 32);
      const float val = acc + brow;
      const float fv1 = __shfl_xor(val, 1);
      const float fv2 = __shfl_xor(val, 2);
      const float fv3 = __shfl_xor(val, 3);
      if (act) {
        const float i_s = fsig(val);
        const float f_s = fsig(fv1);
        const float gt  = ftnh(fv2);
        const float o_s = fsig(fv3);
        creg = f_s*creg + i_s*gt;
        const float hnew = o_s*ftnh(creg);
        const int hidx = b*HB1 + e;
        const u64 pkt = ((u64)(u32)(t+1) << 32) | (u64)__float_as_uint(hnew);
        exst(exS + (size_t)((t+1) & 3)*HSZ + hidx, pkt);
        const int trow = dir ? (T_SEQ-1-t) : t;
        out[4096 + (size_t)trow*1024 + dir*HSZ + hidx] = hnew;   // top-layer outputs
        if (t == T_SEQ-1) {
          out[1024 + dir*HSZ + hidx]        = creg;   // cell_memories layer 1
          out[2048 + 1024 + dir*HSZ + hidx] = hnew;   // hidden_states layer 1
        }
      }
    }
  }
}

// ---------------- launch ----------------
extern "C" void kernel_launch(void* const* d_in, const int* in_sizes, int n_in,
                              void* d_out, int out_size, void* d_ws, size_t ws_size,
                              hipStream_t stream)
{
  const float* emb   = (const float*)d_in[0];
  const float* fWih0 = (const float*)d_in[1];
  const float* fWhh0 = (const float*)d_in[2];
  const float* fbih0 = (const float*)d_in[3];
  const float* fbhh0 = (const float*)d_in[4];
  const float* fWih1 = (const float*)d_in[5];
  const float* fWhh1 = (const float*)d_in[6];
  const float* fbih1 = (const float*)d_in[7];
  const float* fbhh1 = (const float*)d_in[8];
  const float* bWih0 = (const float*)d_in[9];
  const float* bWhh0 = (const float*)d_in[10];
  const float* bbih0 = (const float*)d_in[11];
  const float* bbhh0 = (const float*)d_in[12];
  const float* bWih1 = (const float*)d_in[13];
  const float* bWhh1 = (const float*)d_in[14];
  const float* bbih1 = (const float*)d_in[15];
  const float* bbhh1 = (const float*)d_in[16];
  float* out = (float*)d_out;

  // workspace: P[2][4096][2048] fp32 (67 MB), exchange ex0/ex1 [2][4][512] u64, progress flags
  float* P_f = (float*)d_ws;
  float* P_b = P_f + (size_t)T_SEQ*NGATE;
  u64*   ex0 = (u64*)(P_b + (size_t)T_SEQ*NGATE);
  u64*   ex1 = ex0 + 2*4*HSZ;
  u32*   prog0 = (u32*)(ex1 + 2*4*HSZ);
  u32*   prog1 = prog0 + 2*NB0;

  init_sync_kernel<<<8, 1024, 0, stream>>>(ex0, prog0);

  // layer-0 input projections for both directions (bwd reads P reversed in time)
  gemm_bias_kernel<<<dim3(32,16,2), 256, 0, stream>>>(
      emb, emb, fWih0, bWih0, fbih0, fbhh0, bbih0, bbhh0, P_f, P_b, DIN);

  // fused pipelined recurrence: L0 fwd/bwd + L1 fwd/bwd in one persistent launch
  fused_recur_kernel<<<2*NB0 + 2*NB1, 256, 0, stream>>>(
      fWhh0, bWhh0,
      fWih1, fWhh1, fbih1, fbhh1,
      bWih1, bWhh1, bbih1, bbhh1,
      P_f, P_b, ex0, ex1, prog0, prog1, out);
}